// Round 5
// baseline (208.618 us; speedup 1.0000x reference)
//
#include <hip/hip_runtime.h>

typedef unsigned long long ull;

#define HH 256
#define WW 256
#define PLANE (HH*WW)
#define TILE_R 32
#define TILE_C 64
#define TT 8
#define ER (TILE_R + 2*TT)   // 48 ext rows
#define EC (TILE_C + 2*TT)   // 80 ext cols (uv-pairs per row)
#define NCP (EC/2)           // 40 col-pairs per row
#define NRG 24               // row groups (1024-thread block)
#define RPT (ER/NRG)         // 2 rows per thread
#define NTHR 1024
#define LSZ (4 + ER*EC*2 + 4)   // floats: front pad + tile + end pad = 7688

#define RING_OFS (2u*1024u*1024u)   // float offset of ring slot 1 (8 MB)
#define FLAG_OFS (4u*1024u*1024u)   // float offset of flag array (16 MB)
#define RIMG (HH*(WW/2)*4)          // floats per interleaved ring image (131072)

struct HS { float2 hu, hv, cu, cv; };

// one interleaved row: horizontal [1,2,1] sums for u,v over the thread's 2 cols
// q points at float index of col pair `base` (16B aligned)
__device__ __forceinline__ HS hrow2(const float* q) {
    float2 L = *(const float2*)(q - 2);   // col base-1 (u,v)
    float4 M = *(const float4*)(q);       // cols base, base+1
    float2 R = *(const float2*)(q + 4);   // col base+2
    HS h;
    h.hu = make_float2(fmaf(2.f, M.x, L.x) + M.z, fmaf(2.f, M.z, M.x) + R.x);
    h.hv = make_float2(fmaf(2.f, M.y, L.y) + M.w, fmaf(2.f, M.w, M.y) + R.y);
    h.cu = make_float2(M.x, M.z);
    h.cv = make_float2(M.y, M.w);
    return h;
}

__global__ __launch_bounds__(NTHR, 1)
void hs_mega(const float* __restrict__ x,     // (8,3,256,256): It, Ix, Iy
             const float* __restrict__ est,   // (8,2,256,256): u0, v0
             float* __restrict__ out,         // (8,2,256,256)
             float* __restrict__ ws)          // rings (double-buffered) + flags
{
    __shared__ __align__(16) float s0[LSZ];
    __shared__ __align__(16) float s1[LSZ];

    const int img = blockIdx.x, cs = blockIdx.y, rb = blockIdx.z;
    const int tid = threadIdx.x;
    const int er0 = rb*TILE_R - TT;
    const int ec0 = cs*TILE_C - TT;
    const int blin = (img*4 + cs)*8 + rb;      // 0..255
    unsigned* flags = (unsigned*)(ws + FLAG_OFS);

    // neighbor block id for the 8 poller threads (same image, 8-neighborhood)
    int nb = -1;
    if (tid < 8) {
        int t = (tid < 4) ? tid : tid + 1;     // skip (0,0)
        int dr = t/3 - 1, dc = t%3 - 1;
        int nrb = rb + dr, ncs = cs + dc;
        if (nrb >= 0 && nrb < 8 && ncs >= 0 && ncs < 4)
            nb = (img*4 + ncs)*8 + nrb;
    }

    // ---- per-thread sweep geometry: 2 adjacent uv-cols x RPT rows ----
    const int cp = tid % NCP;          // 0..39
    const int rg = tid / NCP;          // 0..25 (rg>=24 -> idle in sweep)
    const bool active = (rg < NRG);
    const int r0   = (active ? rg : 0) * RPT;
    const int fb   = 4 + 4*cp;         // float index of col pair in row 0

    // ---- per-pixel update coefficients, computed ONCE, live in registers ----
    float2 ca[RPT], cb[RPT], cc[RPT], cd[RPT], ce[RPT];
    {
        const float* __restrict__ xit = x + img*3*PLANE;
        const float* __restrict__ xix = xit + PLANE;
        const float* __restrict__ xiy = xix + PLANE;
        #pragma unroll
        for (int i = 0; i < RPT; ++i) {
            int gr = er0 + r0 + i;
            #pragma unroll
            for (int j = 0; j < 2; ++j) {
                int gc = ec0 + 2*cp + j;
                float A=0.f, B=0.f, C=0.f, D=0.f, E=0.f;
                if (active && gr >= 0 && gr < HH && gc >= 0 && gc < WW) {
                    int q = gr*WW + gc;
                    float it = xit[q], ix = xix[q], iy = xiy[q];
                    float rd = 1.0f / (1.0f + ix*ix + iy*iy);
                    const float s12 = 1.0f/12.0f;
                    A = (1.0f - ix*ix*rd) * s12;
                    B = (ix*iy*rd) * s12;
                    C = ix*it*rd;
                    D = (1.0f - iy*iy*rd) * s12;
                    E = iy*it*rd;
                }
                if (j == 0) { ca[i].x=A; cb[i].x=B; cc[i].x=C; cd[i].x=D; ce[i].x=E; }
                else        { ca[i].y=A; cb[i].y=B; cc[i].y=C; cd[i].y=D; ce[i].y=E; }
            }
        }
    }

    // ---- initial full ext-tile stage from est (interleave on the fly) ----
    {
        const float* __restrict__ eu = est + img*2*PLANE;
        const float* __restrict__ ev = eu + PLANE;
        for (int k = tid; k < ER*NCP; k += NTHR) {           // 1920 chunks
            int r = k / NCP, c = k - r*NCP;
            int gr = er0 + r, gc = ec0 + 2*c;
            float2 uu = make_float2(0.f,0.f), vv = make_float2(0.f,0.f);
            if (gr >= 0 && gr < HH && gc >= 0 && gc < WW) {  // gc even -> pair in-bounds
                uu = *(const float2*)(eu + gr*WW + gc);
                vv = *(const float2*)(ev + gr*WW + gc);
            }
            *(float4*)(s0 + 4 + 160*r + 4*c) = make_float4(uu.x, vv.x, uu.y, vv.y);
        }
    }
    __syncthreads();

    for (int p = 0; p < 13; ++p) {
        const int niter = (p < 12) ? TT : 4;

        // ---- niter iterations fully in LDS (ping-pong), 1 barrier each ----
        for (int s = 1; s <= niter; ++s) {
            const float* __restrict__ rbuf = ((s-1)&1) ? s1 : s0;
            float* __restrict__ wbuf = (s&1) ? s1 : s0;
            if (active) {
                const float* qb = rbuf + fb;
                HS A, B;
                {
                    int rm = (r0 == 0) ? 0 : r0 - 1;
                    A = hrow2(qb + 160*rm);
                    B = hrow2(qb + 160*r0);
                }
                #pragma unroll
                for (int i = 0; i < RPT; ++i) {
                    int rr = r0 + i + 1;
                    if (rr > ER-1) rr = ER-1;
                    HS N = hrow2(qb + 160*rr);
                    float tux = fmaf(-4.f, B.cu.x, fmaf(2.f, B.hu.x, A.hu.x) + N.hu.x);
                    float tuy = fmaf(-4.f, B.cu.y, fmaf(2.f, B.hu.y, A.hu.y) + N.hu.y);
                    float tvx = fmaf(-4.f, B.cv.x, fmaf(2.f, B.hv.x, A.hv.x) + N.hv.x);
                    float tvy = fmaf(-4.f, B.cv.y, fmaf(2.f, B.hv.y, A.hv.y) + N.hv.y);
                    float2 un, vn;
                    un.x = fmaf(ca[i].x, tux, -fmaf(cb[i].x, tvx, cc[i].x));
                    un.y = fmaf(ca[i].y, tuy, -fmaf(cb[i].y, tvy, cc[i].y));
                    vn.x = fmaf(cd[i].x, tvx, -fmaf(cb[i].x, tux, ce[i].x));
                    vn.y = fmaf(cd[i].y, tvy, -fmaf(cb[i].y, tuy, ce[i].y));
                    *(float4*)(wbuf + 160*(r0 + i) + fb) = make_float4(un.x, vn.x, un.y, vn.y);
                    A.hu = B.hu; A.hv = B.hv;
                    B = N;
                }
            }
            __syncthreads();
        }
        // result now in s0 (niter even)

        if (p < 12) {
            float* ring = ws + (unsigned)(p & 1) * RING_OFS + img*RIMG;

            // ---- write depth-8 ring of inner tile (coherent 8B stores) ----
            for (int k = tid; k < 640; k += NTHR) {
                int m = k; int r, c2;
                if (m < 256)      { r = m >> 5;              c2 = m & 31; }
                else if (m < 512) { r = 24 + ((m-256) >> 5); c2 = (m-256) & 31; }
                else { int mm = m - 512; r = 8 + (mm >> 3); int t = mm & 7; c2 = (t < 4) ? t : 24 + t; }
                const float* sp = s0 + 4 + 160*(r + TT) + 4*(c2 + 4);  // ext col pair = c2+4
                float* gp = ring + ((rb*TILE_R + r)*(WW/2) + cs*(TILE_C/2) + c2)*4;
                __hip_atomic_store((ull*)gp,     *(const ull*)sp,       __ATOMIC_RELAXED, __HIP_MEMORY_SCOPE_AGENT);
                __hip_atomic_store((ull*)gp + 1, *(const ull*)(sp + 2), __ATOMIC_RELAXED, __HIP_MEMORY_SCOPE_AGENT);
            }
            asm volatile("s_waitcnt vmcnt(0)" ::: "memory");   // per-wave drain of ring stores
            __syncthreads();
            if (tid == 0)
                __hip_atomic_store(&flags[p*256 + blin], 0x5eed0100u + (unsigned)p,
                                   __ATOMIC_RELAXED, __HIP_MEMORY_SCOPE_AGENT);
            asm volatile("" ::: "memory");
            if (tid < 8 && nb >= 0) {
                const unsigned tgt = 0x5eed0100u + (unsigned)p;
                while (__hip_atomic_load(&flags[p*256 + nb],
                                         __ATOMIC_RELAXED, __HIP_MEMORY_SCOPE_AGENT) != tgt)
                    __builtin_amdgcn_s_sleep(1);
            }
            __syncthreads();

            // ---- restage ext halo ring from neighbors (coherent 8B loads) ----
            for (int k = tid; k < 896; k += NTHR) {
                int m = k; int r, c2;
                if (m < 320)      { r = m / 40;              c2 = m - (m/40)*40; }
                else if (m < 640) { int mm = m-320; r = 40 + mm/40; c2 = mm - (mm/40)*40; }
                else { int mm = m - 640; r = 8 + (mm >> 3); int t = mm & 7; c2 = (t < 4) ? t : 32 + t; }
                int gr = er0 + r, gc2 = cs*(TILE_C/2) - 4 + c2;
                ull v0 = 0, v1 = 0;
                if (gr >= 0 && gr < HH && gc2 >= 0 && gc2 < WW/2) {
                    const float* gp = ring + (gr*(WW/2) + gc2)*4;
                    v0 = __hip_atomic_load((const ull*)gp,     __ATOMIC_RELAXED, __HIP_MEMORY_SCOPE_AGENT);
                    v1 = __hip_atomic_load((const ull*)gp + 1, __ATOMIC_RELAXED, __HIP_MEMORY_SCOPE_AGENT);
                }
                float* sp = s0 + 4 + 160*r + 4*c2;
                *(ull*)sp = v0;
                *(ull*)(sp + 2) = v1;
            }
            __syncthreads();
        }
    }

    // ---- final: de-interleave inner tile to planar out ----
    {
        float* ou = out + img*2*PLANE;
        float* ov = ou + PLANE;
        for (int k = tid; k < 1024; k += NTHR) {
            int r = k >> 5, c2 = k & 31;
            float4 V = *(const float4*)(s0 + 4 + 160*(r + TT) + 4*(c2 + 4));
            int q = (rb*TILE_R + r)*WW + cs*TILE_C + 2*c2;
            *(float2*)(ou + q) = make_float2(V.x, V.z);
            *(float2*)(ov + q) = make_float2(V.y, V.w);
        }
    }
}

extern "C" void kernel_launch(void* const* d_in, const int* in_sizes, int n_in,
                              void* d_out, int out_size, void* d_ws, size_t ws_size,
                              hipStream_t stream) {
    const float* x   = (const float*)d_in[0];   // (8,3,256,256) fp32
    const float* est = (const float*)d_in[1];   // (8,2,256,256) fp32
    float* out = (float*)d_out;
    float* ws  = (float*)d_ws;                  // ring slot0 @0, slot1 @8MB, flags @16MB
                                                // flags 0xAA-poisoned each launch: != MAGIC, no reset needed

    dim3 grid(8, WW/TILE_C, HH/TILE_R);         // 256 blocks, all co-resident (1/CU by LDS)
    dim3 blk(NTHR);
    hs_mega<<<grid, blk, 0, stream>>>(x, est, out, ws);
}

// Round 6
// 196.875 us; speedup vs baseline: 1.0596x; 1.0596x over previous
//
#include <hip/hip_runtime.h>

typedef unsigned long long ull;

#define HH 256
#define WW 256
#define PLANE (HH*WW)
#define TILE_R 32
#define TILE_C 64
#define TT 8
#define ER (TILE_R + 2*TT)   // 48 ext rows
#define EC (TILE_C + 2*TT)   // 80 ext cols (uv-pairs per row)
#define NCP (EC/2)           // 40 col-pairs per row
#define NRG 12               // row groups (512-thread block)
#define RPT (ER/NRG)         // 4 rows per thread
#define NTHR 512
#define LSZ (4 + ER*EC*2 + 4)   // floats: front pad + tile + end pad = 7688

#define RING_OFS (2u*1024u*1024u)   // float offset of ring slot 1 (8 MB)
#define FLAG_OFS (4u*1024u*1024u)   // float offset of flag array (16 MB)
#define RIMG (HH*(WW/2)*4)          // floats per interleaved ring image (131072)

__global__ __launch_bounds__(NTHR, 2)
void hs_mega(const float* __restrict__ x,     // (8,3,256,256): It, Ix, Iy
             const float* __restrict__ est,   // (8,2,256,256): u0, v0
             float* __restrict__ out,         // (8,2,256,256)
             float* __restrict__ ws)          // rings (double-buffered) + flags
{
    __shared__ __align__(16) float s0[LSZ];
    __shared__ __align__(16) float s1[LSZ];

    const int img = blockIdx.x, cs = blockIdx.y, rb = blockIdx.z;
    const int tid = threadIdx.x;
    const int er0 = rb*TILE_R - TT;
    const int ec0 = cs*TILE_C - TT;
    const int blin = (img*4 + cs)*8 + rb;      // 0..255
    unsigned* flags = (unsigned*)(ws + FLAG_OFS);

    // neighbor block id for the 8 poller threads (same image, 8-neighborhood)
    int nb = -1;
    if (tid < 8) {
        int t = (tid < 4) ? tid : tid + 1;     // skip (0,0)
        int dr = t/3 - 1, dc = t%3 - 1;
        int nrb = rb + dr, ncs = cs + dc;
        if (nrb >= 0 && nrb < 8 && ncs >= 0 && ncs < 4)
            nb = (img*4 + ncs)*8 + nrb;
    }

    // ---- per-thread sweep geometry: 2 adjacent uv-cols x RPT rows ----
    const int cp = tid % NCP;          // 0..39
    const int rg = tid / NCP;          // 0..12 (rg==12 -> idle in sweep)
    const bool active = (rg < NRG);
    const int r0   = (active ? rg : 0) * RPT;
    const int fb   = 4 + 4*cp;         // float index of col pair in row 0

    // ---- per-pixel update coefficients, computed ONCE, live in registers ----
    float2 ca[RPT], cb[RPT], cc[RPT], cd[RPT], ce[RPT];
    {
        const float* __restrict__ xit = x + img*3*PLANE;
        const float* __restrict__ xix = xit + PLANE;
        const float* __restrict__ xiy = xix + PLANE;
        #pragma unroll
        for (int i = 0; i < RPT; ++i) {
            int gr = er0 + r0 + i;
            #pragma unroll
            for (int j = 0; j < 2; ++j) {
                int gc = ec0 + 2*cp + j;
                float A=0.f, B=0.f, C=0.f, D=0.f, E=0.f;
                if (active && gr >= 0 && gr < HH && gc >= 0 && gc < WW) {
                    int q = gr*WW + gc;
                    float it = xit[q], ix = xix[q], iy = xiy[q];
                    float rd = 1.0f / (1.0f + ix*ix + iy*iy);
                    const float s12 = 1.0f/12.0f;
                    A = (1.0f - ix*ix*rd) * s12;
                    B = (ix*iy*rd) * s12;
                    C = ix*it*rd;
                    D = (1.0f - iy*iy*rd) * s12;
                    E = iy*it*rd;
                }
                if (j == 0) { ca[i].x=A; cb[i].x=B; cc[i].x=C; cd[i].x=D; ce[i].x=E; }
                else        { ca[i].y=A; cb[i].y=B; cc[i].y=C; cd[i].y=D; ce[i].y=E; }
            }
        }
    }

    // ---- initial full ext-tile stage from est (interleave on the fly) ----
    {
        const float* __restrict__ eu = est + img*2*PLANE;
        const float* __restrict__ ev = eu + PLANE;
        for (int k = tid; k < ER*NCP; k += NTHR) {           // 1920 chunks
            int r = k / NCP, c = k - r*NCP;
            int gr = er0 + r, gc = ec0 + 2*c;
            float2 uu = make_float2(0.f,0.f), vv = make_float2(0.f,0.f);
            if (gr >= 0 && gr < HH && gc >= 0 && gc < WW) {  // gc even -> pair in-bounds
                uu = *(const float2*)(eu + gr*WW + gc);
                vv = *(const float2*)(ev + gr*WW + gc);
            }
            *(float4*)(s0 + 4 + 160*r + 4*c) = make_float4(uu.x, vv.x, uu.y, vv.y);
        }
    }
    __syncthreads();

    for (int p = 0; p < 13; ++p) {
        const int niter = (p < 12) ? TT : 4;

        // ---- niter iterations fully in LDS (ping-pong), 1 barrier each ----
        for (int s = 1; s <= niter; ++s) {
            const float* __restrict__ rbuf = ((s-1)&1) ? s1 : s0;
            float* __restrict__ wbuf = (s&1) ? s1 : s0;
            if (active) {
                const float* qb = rbuf + fb;

                // -- phase 1: issue ALL row loads (18 independent ds ops) --
                const float* pr[RPT+2];
                {
                    int rm = (r0 == 0) ? 0 : r0 - 1;
                    pr[0] = qb + 160*rm;
                    pr[1] = qb + 160*r0;
                    #pragma unroll
                    for (int i = 0; i < RPT; ++i) {
                        int rr = r0 + i + 1;
                        if (rr > ER-1) rr = ER-1;
                        pr[i+2] = qb + 160*rr;
                    }
                }
                float2 L[RPT+2]; float4 M[RPT+2]; float2 R[RPT+2];
                #pragma unroll
                for (int i = 0; i < RPT+2; ++i) {
                    L[i] = *(const float2*)(pr[i] - 2);
                    M[i] = *(const float4*)(pr[i]);
                    R[i] = *(const float2*)(pr[i] + 4);
                }

                // -- phase 2: horizontal [1,2,1] sums (VALU only) --
                float2 hu[RPT+2], hv[RPT+2];
                #pragma unroll
                for (int i = 0; i < RPT+2; ++i) {
                    hu[i] = make_float2(fmaf(2.f, M[i].x, L[i].x) + M[i].z,
                                        fmaf(2.f, M[i].z, M[i].x) + R[i].x);
                    hv[i] = make_float2(fmaf(2.f, M[i].y, L[i].y) + M[i].w,
                                        fmaf(2.f, M[i].w, M[i].y) + R[i].y);
                }

                // -- phase 3: vertical combine + coupled update + write --
                #pragma unroll
                for (int i = 0; i < RPT; ++i) {
                    float tux = fmaf(-4.f, M[i+1].x, fmaf(2.f, hu[i+1].x, hu[i].x) + hu[i+2].x);
                    float tuy = fmaf(-4.f, M[i+1].z, fmaf(2.f, hu[i+1].y, hu[i].y) + hu[i+2].y);
                    float tvx = fmaf(-4.f, M[i+1].y, fmaf(2.f, hv[i+1].x, hv[i].x) + hv[i+2].x);
                    float tvy = fmaf(-4.f, M[i+1].w, fmaf(2.f, hv[i+1].y, hv[i].y) + hv[i+2].y);
                    float2 un, vn;
                    un.x = fmaf(ca[i].x, tux, -fmaf(cb[i].x, tvx, cc[i].x));
                    un.y = fmaf(ca[i].y, tuy, -fmaf(cb[i].y, tvy, cc[i].y));
                    vn.x = fmaf(cd[i].x, tvx, -fmaf(cb[i].x, tux, ce[i].x));
                    vn.y = fmaf(cd[i].y, tvy, -fmaf(cb[i].y, tuy, ce[i].y));
                    *(float4*)(wbuf + 160*(r0 + i) + fb) = make_float4(un.x, vn.x, un.y, vn.y);
                }
            }
            __syncthreads();
        }
        // result now in s0 (niter even)

        if (p < 12) {
            float* ring = ws + (unsigned)(p & 1) * RING_OFS + img*RIMG;

            // ---- write depth-8 ring of inner tile (coherent 8B stores) ----
            for (int k = tid; k < 640; k += NTHR) {
                int m = k; int r, c2;
                if (m < 256)      { r = m >> 5;              c2 = m & 31; }
                else if (m < 512) { r = 24 + ((m-256) >> 5); c2 = (m-256) & 31; }
                else { int mm = m - 512; r = 8 + (mm >> 3); int t = mm & 7; c2 = (t < 4) ? t : 24 + t; }
                const float* sp = s0 + 4 + 160*(r + TT) + 4*(c2 + 4);  // ext col pair = c2+4
                float* gp = ring + ((rb*TILE_R + r)*(WW/2) + cs*(TILE_C/2) + c2)*4;
                __hip_atomic_store((ull*)gp,     *(const ull*)sp,       __ATOMIC_RELAXED, __HIP_MEMORY_SCOPE_AGENT);
                __hip_atomic_store((ull*)gp + 1, *(const ull*)(sp + 2), __ATOMIC_RELAXED, __HIP_MEMORY_SCOPE_AGENT);
            }
            asm volatile("s_waitcnt vmcnt(0)" ::: "memory");   // per-wave drain of ring stores
            __syncthreads();
            if (tid == 0)
                __hip_atomic_store(&flags[p*256 + blin], 0x5eed0100u + (unsigned)p,
                                   __ATOMIC_RELAXED, __HIP_MEMORY_SCOPE_AGENT);
            asm volatile("" ::: "memory");
            if (tid < 8 && nb >= 0) {
                const unsigned tgt = 0x5eed0100u + (unsigned)p;
                while (__hip_atomic_load(&flags[p*256 + nb],
                                         __ATOMIC_RELAXED, __HIP_MEMORY_SCOPE_AGENT) != tgt)
                    __builtin_amdgcn_s_sleep(1);
            }
            __syncthreads();

            // ---- restage ext halo ring from neighbors (coherent 8B loads) ----
            for (int k = tid; k < 896; k += NTHR) {
                int m = k; int r, c2;
                if (m < 320)      { r = m / 40;              c2 = m - (m/40)*40; }
                else if (m < 640) { int mm = m-320; r = 40 + mm/40; c2 = mm - (mm/40)*40; }
                else { int mm = m - 640; r = 8 + (mm >> 3); int t = mm & 7; c2 = (t < 4) ? t : 32 + t; }
                int gr = er0 + r, gc2 = cs*(TILE_C/2) - 4 + c2;
                ull v0 = 0, v1 = 0;
                if (gr >= 0 && gr < HH && gc2 >= 0 && gc2 < WW/2) {
                    const float* gp = ring + (gr*(WW/2) + gc2)*4;
                    v0 = __hip_atomic_load((const ull*)gp,     __ATOMIC_RELAXED, __HIP_MEMORY_SCOPE_AGENT);
                    v1 = __hip_atomic_load((const ull*)gp + 1, __ATOMIC_RELAXED, __HIP_MEMORY_SCOPE_AGENT);
                }
                float* sp = s0 + 4 + 160*r + 4*c2;
                *(ull*)sp = v0;
                *(ull*)(sp + 2) = v1;
            }
            __syncthreads();
        }
    }

    // ---- final: de-interleave inner tile to planar out ----
    {
        float* ou = out + img*2*PLANE;
        float* ov = ou + PLANE;
        for (int k = tid; k < 1024; k += NTHR) {
            int r = k >> 5, c2 = k & 31;
            float4 V = *(const float4*)(s0 + 4 + 160*(r + TT) + 4*(c2 + 4));
            int q = (rb*TILE_R + r)*WW + cs*TILE_C + 2*c2;
            *(float2*)(ou + q) = make_float2(V.x, V.z);
            *(float2*)(ov + q) = make_float2(V.y, V.w);
        }
    }
}

extern "C" void kernel_launch(void* const* d_in, const int* in_sizes, int n_in,
                              void* d_out, int out_size, void* d_ws, size_t ws_size,
                              hipStream_t stream) {
    const float* x   = (const float*)d_in[0];   // (8,3,256,256) fp32
    const float* est = (const float*)d_in[1];   // (8,2,256,256) fp32
    float* out = (float*)d_out;
    float* ws  = (float*)d_ws;                  // ring slot0 @0, slot1 @8MB, flags @16MB
                                                // flags 0xAA-poisoned each launch: != MAGIC, no reset needed

    dim3 grid(8, WW/TILE_C, HH/TILE_R);         // 256 blocks, all co-resident (1/CU by LDS)
    dim3 blk(NTHR);
    hs_mega<<<grid, blk, 0, stream>>>(x, est, out, ws);
}